// Round 13
// baseline (261.118 us; speedup 1.0000x reference)
//
#include <hip/hip_runtime.h>
#include <hip/hip_bf16.h>
#include <math.h>

#define BB  2
#define TT  2048
#define DDE 1024
#define NHH 16
#define HDD 64

typedef __bf16 bf16_t;
typedef __attribute__((ext_vector_type(8))) __bf16 bf16x8;
typedef __attribute__((ext_vector_type(4))) __bf16 bf16x4;
typedef __attribute__((ext_vector_type(4))) float  f32x4;

#define MFMA(a, b, c) __builtin_amdgcn_mfma_f32_16x16x32_bf16((a), (b), (c), 0, 0, 0)

// counted waits: loads for the NEXT tile stay in flight across barriers (T4)
#define WAIT_VM6()   asm volatile("s_waitcnt vmcnt(6)" ::: "memory")
#define WAIT_VM4()   asm volatile("s_waitcnt vmcnt(4)" ::: "memory")
#define WAIT_VM0()   asm volatile("s_waitcnt vmcnt(0)" ::: "memory")
#define WAIT_LGKM0() asm volatile("s_waitcnt lgkmcnt(0)" ::: "memory")

// raw workgroup barrier (no vmcnt drain), fenced against compiler reordering
__device__ inline void wg_barrier() {
    __builtin_amdgcn_sched_barrier(0);
    __builtin_amdgcn_s_barrier();
    __builtin_amdgcn_sched_barrier(0);
}

// pack 2 f32 -> 1 u32 of 2 bf16 (RNE), no builtin on gfx950
__device__ inline unsigned int cvtpk(float a, float b) {
    unsigned int r;
    asm("v_cvt_pk_bf16_f32 %0, %1, %2" : "=v"(r) : "v"(a), "v"(b));
    return r;
}

// single-instruction 2^x (exact; denormals flush->0, fine for softmax)
__device__ inline float fexp2(float x) {
    float r;
    asm("v_exp_f32 %0, %1" : "=v"(r) : "v"(x));
    return r;
}

// v_permlane16_swap_b32: swaps a's odd 16-lane rows with b's even 16-lane
// rows.  After: a = {a.r0, b.r0, a.r2, b.r2}, b = {a.r1, b.r1, a.r3, b.r3}.
__device__ inline void pl16swap(unsigned int &a, unsigned int &b) {
    asm("v_permlane16_swap_b32 %0, %1" : "+v"(a), "+v"(b));
}

__device__ inline void gll16(const bf16_t* g, unsigned short* l) {
    __builtin_amdgcn_global_load_lds(
        (const __attribute__((address_space(1))) void*)g,
        (__attribute__((address_space(3))) void*)l, 16, 0, 0);
}

// Stage [ROWS x 64] bf16 tile (row stride gstride elems) into LDS via
// global_load_lds, chunk-swizzled: LDS elem [r][ (c ^ (r&7))*8 + j ].
// Per-wave gll16 count: ROWS/(NW*8).
template<int ROWS, int NW = 4>
__device__ inline void stage_tile(const bf16_t* g0, size_t gstride,
                                  unsigned short* lds, int wave, int lane)
{
    const int r8 = lane >> 3;
    const int ck = (lane & 7) ^ r8;
    constexpr int RW = ROWS / NW;
    const bf16_t* g = g0 + (size_t)(wave * RW + r8) * gstride + ck * 8;
    unsigned short* l = lds + wave * RW * 64 + lane * 8;
    #pragma unroll
    for (int i = 0; i < RW / 8; ++i)
        gll16(g + (size_t)(i * 8) * gstride, l + i * 512);
}

// ---------------------------------------------------------------------------
// fused fp32->bf16 conversion of x, w_attn, w_k2, w_proj into the contiguous
// ws region starting at xb.  Segment boundaries are multiples of 1024 elems.
// ---------------------------------------------------------------------------
__global__ __launch_bounds__(256) void cvt_all(
    const float* __restrict__ x, const float* __restrict__ wa,
    const float* __restrict__ wk, const float* __restrict__ wp,
    bf16_t* __restrict__ out)
{
    const size_t NX  = (size_t)BB*TT*DDE;
    const size_t NWA = (size_t)2*DDE*DDE;
    const size_t NW  = (size_t)DDE*DDE;
    const size_t e = ((size_t)blockIdx.x * 256 + threadIdx.x) * 4;
    const float* src;
    if (e < NX)                 src = x  + e;
    else if (e < NX + NWA)      src = wa + (e - NX);
    else if (e < NX + NWA + NW) src = wk + (e - NX - NWA);
    else                        src = wp + (e - NX - NWA - NW);
    float4 v = *(const float4*)src;
    bf16x4 o;
    o[0] = (bf16_t)v.x; o[1] = (bf16_t)v.y;
    o[2] = (bf16_t)v.z; o[3] = (bf16_t)v.w;
    *(bf16x4*)(out + e) = o;
}

// ---------------------------------------------------------------------------
// Per-head 64x64 transpose: dst[bh][d][t] = src[b][t][h*64+d].
// ---------------------------------------------------------------------------
__global__ __launch_bounds__(256) void transpose_head(
    const bf16_t* __restrict__ src, bf16_t* __restrict__ dst)
{
    const int t0 = blockIdx.x * 64, h = blockIdx.y, b = blockIdx.z;
    const int tid = threadIdx.x;
    __shared__ __align__(16) bf16_t tile[64 * 64];

    #pragma unroll
    for (int it = 0; it < 2; ++it) {
        const int t = it * 32 + (tid >> 3);
        const int cw = tid & 7;
        const int slot = (cw + (t >> 3)) & 7;
        bf16x8 v = *(const bf16x8*)(src + (size_t)(b*TT + t0 + t)*DDE + h*HDD + cw*8);
        *(bf16x8*)(tile + t*64 + slot*8) = v;
    }
    __syncthreads();
    const int bh = b * NHH + h;
    #pragma unroll
    for (int it = 0; it < 2; ++it) {
        const int d = it * 32 + (tid >> 3);
        const int co = tid & 7;
        const int slot = ((d >> 3) + co) & 7;
        bf16x8 o;
        #pragma unroll
        for (int j = 0; j < 8; ++j)
            o[j] = tile[(co*8 + j)*64 + slot*8 + (d & 7)];
        *(bf16x8*)(dst + (size_t)(bh*64 + d)*TT + t0 + co*8) = o;
    }
}

// ---------------------------------------------------------------------------
// E-transpose: etg[bh][d][t] = x[t][d] - n[t-1][d]  (0 at t==0),
// where n = yarb (normalized AR output, written by attn_ar).
// ---------------------------------------------------------------------------
__global__ __launch_bounds__(256) void build_etg(
    const bf16_t* __restrict__ yarb, const bf16_t* __restrict__ xb,
    bf16_t* __restrict__ etg)
{
    const int t0 = blockIdx.x * 64, h = blockIdx.y, b = blockIdx.z;
    const int tid = threadIdx.x;
    const int bh = b * NHH + h;
    __shared__ __align__(16) bf16_t tile[64 * 64];

    #pragma unroll
    for (int it = 0; it < 2; ++it) {
        const int t = it * 32 + (tid >> 3);
        const int cw = tid & 7;
        const int slot = (cw + (t >> 3)) & 7;
        const int tg = t0 + t;
        bf16x8 ev;
        if (tg == 0) {
            #pragma unroll
            for (int u = 0; u < 8; ++u) ev[u] = (bf16_t)0.f;
        } else {
            bf16x8 xv = *(const bf16x8*)(xb   + (size_t)(b*TT + tg)*DDE + h*HDD + cw*8);
            bf16x8 nv = *(const bf16x8*)(yarb + (size_t)(b*TT + tg - 1)*DDE + h*HDD + cw*8);
            #pragma unroll
            for (int u = 0; u < 8; ++u)
                ev[u] = (bf16_t)((float)xv[u] - (float)nv[u]);
        }
        *(bf16x8*)(tile + t*64 + slot*8) = ev;
    }
    __syncthreads();
    #pragma unroll
    for (int it = 0; it < 2; ++it) {
        const int d = it * 32 + (tid >> 3);
        const int co = tid & 7;
        const int slot = ((d >> 3) + co) & 7;
        bf16x8 o;
        #pragma unroll
        for (int j = 0; j < 8; ++j)
            o[j] = tile[(co*8 + j)*64 + slot*8 + (d & 7)];
        *(bf16x8*)(etg + (size_t)(bh*64 + d)*TT + t0 + co*8) = o;
    }
}

// ---------------------------------------------------------------------------
// Fused QKV GEMM, BM=64 x BN=128, BK=64, counted-vmcnt dbuf pipeline
// (round-10/12 proven config: ~46us / 561 TF).  Region by column tile:
//   [0,1024):  q -> qkb = q*0.125*log2(e) (exp2 domain), qab = leaky(q*0.125)
//   [1024,2048): k -> qkb raw
//   [2048,3072): k2 -> kcs[t+1] = sigmoid(k2*0.0025)-0.5 (shifted, row0=0)
// ---------------------------------------------------------------------------
__global__ __launch_bounds__(256) void gemm_qkk2(
    const bf16_t* __restrict__ A, const bf16_t* __restrict__ wab,
    const bf16_t* __restrict__ wkb, const float* __restrict__ b_attn,
    const float* __restrict__ b_k2, bf16_t* __restrict__ qkb,
    bf16_t* __restrict__ qab, bf16_t* __restrict__ kcs)
{
    __shared__ __align__(16) unsigned short As[2][64 * 64];
    __shared__ __align__(16) unsigned short Bs[2][128 * 64];
    const int tid  = threadIdx.x;
    const int wave = tid >> 6, lane = tid & 63;
    const int l15  = lane & 15, quad = lane >> 4;
    // XCD swizzle (bijective: 1536 = 8*192): each XCD owns 8 contiguous
    // m-rows x all 24 n-tiles; per-k-step slab (A 64KB + B 384KB) L2-fits.
    const int lid = (int)blockIdx.y * 24 + (int)blockIdx.x;
    const int s   = (lid & 7) * 192 + (lid >> 3);
    const int bm = (s / 24) * 64, bn = (s % 24) * 128;
    const int wm = (wave & 1) * 32, wn = (wave >> 1) * 64;
    const int region = bn >> 10;
    const int K = DDE;
    constexpr int NST = DDE / 64;   // 16 K-steps

    const bf16_t* W = (region < 2) ? wab + (size_t)bn * K
                                   : wkb + (size_t)(bn - 2048) * K;
    const float* bp = (region < 2) ? b_attn + bn : b_k2 + (bn - 2048);
    const bf16_t* Ab = A + (size_t)bm * K;

    f32x4 acc[2][4];
    #pragma unroll
    for (int i = 0; i < 2; ++i)
        #pragma unroll
        for (int j = 0; j < 4; ++j) acc[i][j] = (f32x4)0.f;

    // prologue: stage K-steps 0 and 1 (6 gll16/wave each: 2 A + 4 B)
    stage_tile<64>(Ab, K, As[0], wave, lane);
    stage_tile<128>(W,  K, Bs[0], wave, lane);
    stage_tile<64>(Ab + 64, K, As[1], wave, lane);
    stage_tile<128>(W  + 64, K, Bs[1], wave, lane);

    for (int t = 0; t < NST; ++t) {
        // wait tile t landed; tile t+1's 6 loads stay in flight
        if (t + 1 < NST) WAIT_VM6(); else WAIT_VM0();
        wg_barrier();
        const unsigned short* Ac = As[t & 1];
        const unsigned short* Bc = Bs[t & 1];
        bf16x8 af[2][2], bfr[4][2];
        #pragma unroll
        for (int mt = 0; mt < 2; ++mt)
            #pragma unroll
            for (int kh = 0; kh < 2; ++kh)
                af[mt][kh] = *(const bf16x8*)(Ac + (wm + mt*16 + l15)*64
                                              + (((kh*4 + quad) ^ (l15 & 7))*8));
        #pragma unroll
        for (int nt = 0; nt < 4; ++nt)
            #pragma unroll
            for (int kh = 0; kh < 2; ++kh)
                bfr[nt][kh] = *(const bf16x8*)(Bc + (wn + nt*16 + l15)*64
                                               + (((kh*4 + quad) ^ (l15 & 7))*8));
        __builtin_amdgcn_s_setprio(1);
        #pragma unroll
        for (int mt = 0; mt < 2; ++mt)
            #pragma unroll
            for (int nt = 0; nt < 4; ++nt) {
                acc[mt][nt] = MFMA(af[mt][0], bfr[nt][0], acc[mt][nt]);
                acc[mt][nt] = MFMA(af[mt][1], bfr[nt][1], acc[mt][nt]);
            }
        __builtin_amdgcn_s_setprio(0);
        // all waves done reading buf[t&1] before restaging into it
        WAIT_LGKM0();
        wg_barrier();
        if (t + 2 < NST) {
            stage_tile<64>(Ab + (t+2)*64, K, As[t & 1], wave, lane);
            stage_tile<128>(W  + (t+2)*64, K, Bs[t & 1], wave, lane);
        }
    }

    #pragma unroll
    for (int nt = 0; nt < 4; ++nt) {
        const int cl = wn + nt*16 + l15;
        const float bj = bp[cl];
        const int cg = bn + cl;
        #pragma unroll
        for (int mt = 0; mt < 2; ++mt)
            #pragma unroll
            for (int r = 0; r < 4; ++r) {
                const int row = bm + wm + mt*16 + quad*4 + r;
                const float v = acc[mt][nt][r] + bj;
                if (region == 0) {
                    qkb[(size_t)row * (2*DDE) + cg] = (bf16_t)(v * 0.180336880f);
                    const float z = v * 0.125f;
                    qab[(size_t)row * DDE + cg] = (bf16_t)((v > 0.f) ? 0.02f*z : z);
                } else if (region == 1) {
                    qkb[(size_t)row * (2*DDE) + cg] = (bf16_t)v;
                } else {
                    const int c2 = cg - 2048;
                    const float kc = 1.f/(1.f + __expf(-v*0.0025f)) - 0.5f;
                    if (((row + 1) & (TT - 1)) != 0)
                        kcs[(size_t)(row + 1) * DDE + c2] = (bf16_t)kc;
                    if ((row & (TT - 1)) == 0)
                        kcs[(size_t)row * DDE + c2] = (bf16_t)0.f;
                }
            }
    }
}

// ---------------------------------------------------------------------------
// proj GEMM, BM=64 x BN=64, BK=64, counted-vmcnt dbuf (fp32 out):
// C = A W^T + 2*bias.  1024 blocks (4/CU by grid, 5/CU by LDS=32KB).
// ---------------------------------------------------------------------------
__global__ __launch_bounds__(256) void gemm_proj(
    const bf16_t* __restrict__ A, const bf16_t* __restrict__ W,
    const float* __restrict__ bias, float* __restrict__ C,
    int M, int N, int K, float bmul)
{
    __shared__ __align__(16) unsigned short As[2][64 * 64];
    __shared__ __align__(16) unsigned short Bs[2][64 * 64];
    const int tid  = threadIdx.x;
    const int wave = tid >> 6, lane = tid & 63;
    const int l15  = lane & 15, quad = lane >> 4;
    // XCD swizzle (bijective: 1024 = 8*128)
    const int lid = (int)blockIdx.y * 16 + (int)blockIdx.x;
    const int s   = (lid & 7) * 128 + (lid >> 3);
    const int bm = (s / 16) * 64, bn = (s % 16) * 64;
    const int wm = (wave & 1) * 32, wn = (wave >> 1) * 32;

    const bf16_t* Ab = A + (size_t)bm * K;
    const bf16_t* Wb = W + (size_t)bn * K;
    const int NST = K / 64;

    f32x4 acc[2][2];
    #pragma unroll
    for (int i = 0; i < 2; ++i)
        #pragma unroll
        for (int j = 0; j < 2; ++j) acc[i][j] = (f32x4)0.f;

    stage_tile<64>(Ab, K, As[0], wave, lane);
    stage_tile<64>(Wb, K, Bs[0], wave, lane);
    stage_tile<64>(Ab + 64, K, As[1], wave, lane);
    stage_tile<64>(Wb + 64, K, Bs[1], wave, lane);

    for (int t = 0; t < NST; ++t) {
        if (t + 1 < NST) WAIT_VM4(); else WAIT_VM0();
        wg_barrier();
        const unsigned short* Ac = As[t & 1];
        const unsigned short* Bc = Bs[t & 1];
        bf16x8 af[2][2], bfr[2][2];
        #pragma unroll
        for (int mt = 0; mt < 2; ++mt)
            #pragma unroll
            for (int kh = 0; kh < 2; ++kh)
                af[mt][kh] = *(const bf16x8*)(Ac + (wm + mt*16 + l15)*64
                                              + (((kh*4 + quad) ^ (l15 & 7))*8));
        #pragma unroll
        for (int nt = 0; nt < 2; ++nt)
            #pragma unroll
            for (int kh = 0; kh < 2; ++kh)
                bfr[nt][kh] = *(const bf16x8*)(Bc + (wn + nt*16 + l15)*64
                                               + (((kh*4 + quad) ^ (l15 & 7))*8));
        __builtin_amdgcn_s_setprio(1);
        #pragma unroll
        for (int mt = 0; mt < 2; ++mt)
            #pragma unroll
            for (int nt = 0; nt < 2; ++nt) {
                acc[mt][nt] = MFMA(af[mt][0], bfr[nt][0], acc[mt][nt]);
                acc[mt][nt] = MFMA(af[mt][1], bfr[nt][1], acc[mt][nt]);
            }
        __builtin_amdgcn_s_setprio(0);
        WAIT_LGKM0();
        wg_barrier();
        if (t + 2 < NST) {
            stage_tile<64>(Ab + (t+2)*64, K, As[t & 1], wave, lane);
            stage_tile<64>(Wb + (t+2)*64, K, Bs[t & 1], wave, lane);
        }
    }

    #pragma unroll
    for (int nt = 0; nt < 2; ++nt) {
        const int col = bn + wn + nt*16 + l15;
        const float bj = bias[col] * bmul;
        #pragma unroll
        for (int mt = 0; mt < 2; ++mt)
            #pragma unroll
            for (int r = 0; r < 4; ++r) {
                const int row = bm + wm + mt*16 + quad*4 + r;
                C[(size_t)row * N + col] = acc[mt][nt][r] + bj;
            }
    }
}

// softmax-exp + mask + bf16 pack + permlane repack: sv (S^T C-layout) -> pa
// (PV A-fragment).  AR variant (exp2-domain scores).
#define AR_SM(SV, PA, QW0)  do {                                            \
    const bool domask = (s0 + 63 > (QW0));                                  \
    const int qg = (QW0) + l15;                                             \
    unsigned int pk[4][2];                                                  \
    _Pragma("unroll")                                                       \
    for (int nt = 0; nt < 4; ++nt) {                                        \
        float pv[4];                                                        \
        _Pragma("unroll")                                                   \
        for (int r = 0; r < 4; ++r) {                                       \
            float pe = fexp2(SV[nt][r]);                                    \
            if (domask) {                                                   \
                const int sg = s0 + nt*16 + quad*4 + r;                     \
                if (sg > qg) pe = 0.f;                                      \
            }                                                               \
            pv[r] = pe;                                                     \
        }                                                                   \
        pk[nt][0] = cvtpk(pv[0], pv[1]);                                    \
        pk[nt][1] = cvtpk(pv[2], pv[3]);                                    \
    }                                                                       \
    _Pragma("unroll")                                                       \
    for (int sc = 0; sc < 2; ++sc) {                                        \
        pl16swap(pk[2*sc][0], pk[2*sc+1][0]);                               \
        pl16swap(pk[2*sc][1], pk[2*sc+1][1]);                               \
        union { unsigned int uu[4]; bf16x8 v; } pu;                         \
        pu.uu[0] = pk[2*sc][0];   pu.uu[1] = pk[2*sc][1];                   \
        pu.uu[2] = pk[2*sc+1][0]; pu.uu[3] = pk[2*sc+1][1];                 \
        PA[sc] = pu.v;                                                      \
    }                                                                       \
} while (0)

// MA variant: p = S + Rr, zero masks (causal + t==0 row).
#define MA_SM(SV, PA, RR, QW0)  do {                                        \
    const bool domask = (s0 + 63 > (QW0));                                  \
    const bool m0 = (myt == 0);                                             \
    const int qg = (QW0) + l15;                                             \
    unsigned int pk[4][2];                                                  \
    _Pragma("unroll")                                                       \
    for (int nt = 0; nt < 4; ++nt) {                                        \
        float pv[4];                                                        \
        _Pragma("unroll")                                                   \
        for (int r = 0; r < 4; ++r) {                                       \
            const int sg = s0 + nt*16 + quad*4 + r;                         \
            float pe = SV[nt][r] + (RR);                                    \
            if (m0 && sg == 0) pe = 0.f;                                    \
            if (domask && sg > qg) pe = 0.f;                                \
            pv[r] = pe;                                                     \
        }                                                                   \
        pk[nt][0] = cvtpk(pv[0], pv[1]);                                    \
        pk[nt][1] = cvtpk(pv[2], pv[3]);                                    \
    }                                                                       \
    _Pragma("unroll")                                                       \
    for (int sc = 0; sc < 2; ++sc) {                                        \
        pl16swap(pk[2*sc][0], pk[2*sc+1][0]);                               \
        pl16swap(pk[2*sc][1], pk[2*sc+1][1]);                               \
        union { unsigned int uu[4]; bf16x8 v; } pu;                         \
        pu.uu[0] = pk[2*sc][0];   pu.uu[1] = pk[2*sc][1];                   \
        pu.uu[2] = pk[2*sc+1][0]; pu.uu[3] = pk[2*sc+1][1];                 \
        PA[sc] = pu.v;                                                      \
    }                                                                       \
} while (0)

// ---------------------------------------------------------------------------
// AR: fixed-max flash attention, work-conserving paired decomposition.
// Block owns q-tiles (p, 31-p); wave takes tile myt = 2*jp + (wave>=4).
// K/V fragments are loaded ONCE per tile and shared by both targets
// (halves ds_read traffic on both-active iterations vs per-unit loads).
// ---------------------------------------------------------------------------
__global__ __launch_bounds__(512, 4) void attn_ar_mfma(
    const bf16_t* __restrict__ qkb, const bf16_t* __restrict__ vtg,
    bf16_t* __restrict__ yarb)
{
    const int h = blockIdx.y, b = blockIdx.z;
    const int p = b ? (15 - (int)blockIdx.x) : (int)blockIdx.x;  // co-CU hedge
    const int qtL = p, qtH = 31 - p;
    const int tid = threadIdx.x, wave = tid >> 6, lane = tid & 63;
    const int l15 = lane & 15, quad = lane >> 4;
    const int wl = wave & 3, wsid = wave >> 2;
    const int qw0L = qtL * 64 + wl * 16;
    const int qw0H = qtH * 64 + wl * 16;
    const int bh = b * NHH + h;

    // [pair][half][K=0/V=1][64*64] = 64 KB; reused as f32 merge scratch.
    __shared__ __align__(16) unsigned short Lds[2][2][2][64 * 64];

    const int nit = qtH + 1;          // kv tiles 0 .. qtH  (>= 17)
    const int npair = (nit + 1) >> 1;

    const bf16_t* kg = qkb + (size_t)(b*TT)*(2*DDE) + DDE + h*HDD;
    const bf16_t* vg = vtg + (size_t)(bh*64)*TT;

    // Q fragments for both targets: direct global->reg.
    const bf16_t* qrowL = qkb + (size_t)(b*TT + qw0L + l15)*(2*DDE) + h*HDD;
    const bf16_t* qrowH = qkb + (size_t)(b*TT + qw0H + l15)*(2*DDE) + h*HDD;
    bf16x8 qfL[2], qfH[2];
    qfL[0] = *(const bf16x8*)(qrowL + quad*8);
    qfL[1] = *(const bf16x8*)(qrowL + (quad + 4)*8);
    qfH[0] = *(const bf16x8*)(qrowH + quad*8);
    qfH[1] = *(const bf16x8*)(qrowH + (quad + 4)*8);
    __builtin_amdgcn_sched_barrier(0);   // pin Q-load issue before staging

    // prologue: pairs 0 (tiles 0,1) and 1 (tiles 2,3); 4 loads/wave/pair
    stage_tile<64, 8>(kg, 2*DDE, &Lds[0][0][0][0], wave, lane);
    stage_tile<64, 8>(vg, TT,    &Lds[0][0][1][0], wave, lane);
    stage_tile<64, 8>(kg + (size_t)64*(2*DDE), 2*DDE, &Lds[0][1][0][0], wave, lane);
    stage_tile<64, 8>(vg + 64, TT, &Lds[0][1][1][0], wave, lane);
    stage_tile<64, 8>(kg + (size_t)2*64*(2*DDE), 2*DDE, &Lds[1][0][0][0], wave, lane);
    stage_tile<64, 8>(vg + 2*64, TT, &Lds[1][0][1][0], wave, lane);
    stage_tile<64, 8>(kg + (size_t)3*64*(2*DDE), 2*DDE, &Lds[1][1][0][0], wave, lane);
    stage_tile<64, 8>(vg + 3*64, TT, &Lds[1][1][1][0], wave, lane);
    WAIT_VM4();            // Q + pair0 landed, pair1 in flight
    wg_barrier();

    f32x4 oH[4], oL[4];
    f32x4 lsH = (f32x4)0.f, lsL = (f32x4)0.f;
    #pragma unroll
    for (int nt = 0; nt < 4; ++nt) { oH[nt] = (f32x4)0.f; oL[nt] = (f32x4)0.f; }
    bf16x8 onesb;
    #pragma unroll
    for (int j = 0; j < 8; ++j) onesb[j] = (bf16_t)1.f;

    // after permlane repack, quad q holds key-chunk cq = bitswap(q)
    const int cq = ((quad & 1) << 1) | (quad >> 1);

    for (int jp = 0; jp < npair; ++jp) {
        if (jp > 0) {
            if (jp + 1 < npair) WAIT_VM4(); else WAIT_VM0();
            wg_barrier();
        }
        const int myt = 2*jp + wsid;
        const int s0 = myt * 64;
        const unsigned short* Kc = &Lds[jp & 1][wsid][0][0];
        const unsigned short* Vc = &Lds[jp & 1][wsid][1][0];

        if (myt <= qtH) {                 // L active => H active (p <= qtH)
            const bool doL = (myt <= p);
            // K fragments once, shared by both targets
            bf16x8 kb[4][2];
            #pragma unroll
            for (int nt = 0; nt < 4; ++nt) {
                const unsigned short* kr = Kc + (nt*16 + l15)*64;
                kb[nt][0] = *(const bf16x8*)(kr + ((quad    ) ^ (l15 & 7))*8);
                kb[nt][1] = *(const bf16x8*)(kr + ((quad + 4) ^ (l15 & 7))*8);
            }
            f32x4 svH[4], svL[4];
            __builtin_amdgcn_s_setprio(1);
            #pragma unroll
            for (int nt = 0; nt < 4; ++nt) {
                f32x4 z = (f32x4)0.f;
                z = MFMA(kb[nt][0], qfH[0], z);
                z = MFMA(kb[nt][1], qfH[1], z);
                svH[nt] = z;
            }
            if (doL) {
                #pragma unroll
                for (int nt = 0; nt < 4; ++nt) {
                    f32x4 z = (f32x4)0.f;
                    z = MFMA(kb[nt][0], qfL[0], z);
                    z = MFMA(kb[nt][1], qfL[1], z);
                    svL[nt] = z;
                }
            }
            __builtin_amdgcn_s_setprio(0);

            bf16x8 paH[2], paL[2];
            AR_SM(svH, paH, qw0H);
            if (doL) AR_SM(svL, paL, qw0L);

            // V fragments once, shared by both targets
            bf16x8 vb[4][2];
            #pragma unroll
            for (int nt = 0; nt < 4; ++nt) {
                const unsigned short* vr = Vc + (nt*16 + l15)*64;
                vb[nt][0] = *(const bf16x8*)(vr + ((cq    ) ^ (l15 & 7))*8);
                vb[nt][1] = *(const bf16x8*)(vr + ((cq + 4) ^ (l15 & 7))*8);
            }
            __builtin_amdgcn_s_setprio(1);
            lsH = MFMA(paH[0], onesb, lsH);
            lsH = MFMA(paH[1], onesb, lsH);
            #pragma unroll
            for (int nt = 0; nt < 4; ++nt) {
                oH[nt] = MFMA(paH[0], vb[nt][0], oH[nt]);
                oH[nt] = MFMA(paH[1], vb[nt][1], oH[nt]);
            }
            if (doL) {
                lsL = MFMA(paL[0], onesb, lsL);
                lsL = MFMA(paL[1], onesb, lsL);
                #pragma unroll
                for (int nt = 0; nt < 4; ++nt) {
                    oL[nt] = MFMA(paL[0], vb[nt][0], oL[nt]);
                    oL[nt] = MFMA(paL[1], vb[nt][1], oL[nt]);
                }
            }
            __builtin_amdgcn_s_setprio(0);
        }

        WAIT_LGKM0();
        wg_barrier();
        if (jp + 2 < npair) {
            const int t0 = 2*(jp + 2);              // always < nit
            const int t1 = min(t0 + 1, nit - 1);    // clamp (uniform vmcnt)
            stage_tile<64, 8>(kg + (size_t)t0*64*(2*DDE), 2*DDE, &Lds[jp & 1][0][0][0], wave, lane);
            stage_tile<64, 8>(vg + t0*64, TT, &Lds[jp & 1][0][1][0], wave, lane);
            stage_tile<64, 8>(kg + (size_t)t1*64*(2*DDE), 2*DDE, &Lds[jp & 1][1][0][0], wave, lane);
            stage_tile<64, 8>(vg + t1*64, TT, &Lds[jp & 1][1][1][0], wave, lane);
        }
    }
    // here: vmcnt==0 (final iter waited VM0, no further stages); LDS reusable.

    // merge partials across the ws-pair: ws=0 ships H-set, ws=1 ships L-set.
    float* S = (float*)&Lds[0][0][0][0];
    float* my = S + (size_t)(wave*64 + lane)*20;
    {
        const f32x4 (&os)[4] = wsid ? oL : oH;
        const f32x4 &lss     = wsid ? lsL : lsH;
        #pragma unroll
        for (int nt = 0; nt < 4; ++nt)
            #pragma unroll
            for (int r = 0; r < 4; ++r) my[nt*4 + r] = os[nt][r];
        #pragma unroll
        for (int r = 0; r < 4; ++r) my[16 + r] = lss[r];
    }
    WAIT_LGKM0();
    wg_barrier();
    const float* peer = S + (size_t)((wave ^ 4)*64 + lane)*20;
    f32x4 (&ok)[4] = wsid ? oH : oL;   // kept set (the one not shipped)
    f32x4 &lsk     = wsid ? lsH : lsL;
    #pragma unroll
    for (int nt = 0; nt < 4; ++nt)
        #pragma unroll
        for (int r = 0; r < 4; ++r) ok[nt][r] += peer[nt*4 + r];
    #pragma unroll
    for (int r = 0; r < 4; ++r) lsk[r] += peer[16 + r];

    // store: ws=0 -> qtL rows, ws=1 -> qtH rows
    const int qt = wsid ? qtH : qtL;
    float inv[4];
    #pragma unroll
    for (int r = 0; r < 4; ++r) inv[r] = 1.f / lsk[r];
    #pragma unroll
    for (int nt = 0; nt < 4; ++nt)
        #pragma unroll
        for (int r = 0; r < 4; ++r) {
            const int row = qt*64 + wl*16 + quad*4 + r;
            const int col = h*HDD + nt*16 + l15;
            yarb[(size_t)(b*TT + row)*DDE + col] = (bf16_t)(ok[nt][r] * inv[r]);
        }
}

// ---------------------------------------------------------------------------
// MA: linear causal attention, same work-conserving paired structure with
// shared K/E fragment loads.  Fused combine epilogue: ysumb = bf16(yarb+o).
// ---------------------------------------------------------------------------
__global__ __launch_bounds__(512, 4) void attn_ma_mfma(
    const bf16_t* __restrict__ qab, const bf16_t* __restrict__ kcs,
    const bf16_t* __restrict__ etg, const bf16_t* __restrict__ yarb,
    bf16_t* __restrict__ ysumb)
{
    const int h = blockIdx.y, b = blockIdx.z;
    const int p = b ? (15 - (int)blockIdx.x) : (int)blockIdx.x;
    const int qtL = p, qtH = 31 - p;
    const int tid = threadIdx.x, wave = tid >> 6, lane = tid & 63;
    const int l15 = lane & 15, quad = lane >> 4;
    const int wl = wave & 3, wsid = wave >> 2;
    const int qw0L = qtL * 64 + wl * 16;
    const int qw0H = qtH * 64 + wl * 16;
    const int bh = b * NHH + h;

    __shared__ __align__(16) unsigned short Lds[2][2][2][64 * 64];

    const int nit = qtH + 1;
    const int npair = (nit + 1) >> 1;

    const bf16_t* kg = kcs + (size_t)(b*TT)*DDE + h*HDD;
    const bf16_t* eg = etg + (size_t)(bh*64)*TT;

    const bf16_t* qrowL = qab + (size_t)(b*TT + qw0L + l15)*DDE + h*HDD;
    const bf16_t* qrowH = qab + (size_t)(b*TT + qw0H + l15)*DDE + h*HDD;
    bf16x8 qfL[2], qfH[2];
    qfL[0] = *(const bf16x8*)(qrowL + quad*8);
    qfL[1] = *(const bf16x8*)(qrowL + (quad + 4)*8);
    qfH[0] = *(const bf16x8*)(qrowH + quad*8);
    qfH[1] = *(const bf16x8*)(qrowH + (quad + 4)*8);
    __builtin_amdgcn_sched_barrier(0);

    stage_tile<64, 8>(kg, DDE, &Lds[0][0][0][0], wave, lane);
    stage_tile<64, 8>(eg, TT,  &Lds[0][0][1][0], wave, lane);
    stage_tile<64, 8>(kg + (size_t)64*DDE, DDE, &Lds[0][1][0][0], wave, lane);
    stage_tile<64, 8>(eg + 64, TT, &Lds[0][1][1][0], wave, lane);
    stage_tile<64, 8>(kg + (size_t)2*64*DDE, DDE, &Lds[1][0][0][0], wave, lane);
    stage_tile<64, 8>(eg + 2*64, TT, &Lds[1][0][1][0], wave, lane);
    stage_tile<64, 8>(kg + (size_t)3*64*DDE, DDE, &Lds[1][1][0][0], wave, lane);
    stage_tile<64, 8>(eg + 3*64, TT, &Lds[1][1][1][0], wave, lane);
    WAIT_VM4();
    wg_barrier();

    // Q row-sums in-register (quad butterfly yields full 64-col sum per row)
    float rsL = 0.f, rsH = 0.f;
    #pragma unroll
    for (int kc = 0; kc < 2; ++kc)
        #pragma unroll
        for (int u = 0; u < 8; ++u) { rsL += (float)qfL[kc][u]; rsH += (float)qfH[kc][u]; }
    rsL += __shfl_xor(rsL, 16); rsL += __shfl_xor(rsL, 32);
    rsH += __shfl_xor(rsH, 16); rsH += __shfl_xor(rsH, 32);
    const float RrL = 0.5f * rsL;
    const float RrH = 0.5f * rsH;

    f32x4 oH[4], oL[4];
    #pragma unroll
    for (int nt = 0; nt < 4; ++nt) { oH[nt] = (f32x4)0.f; oL[nt] = (f32x4)0.f; }

    const int cq = ((quad & 1) << 1) | (quad >> 1);

    for (int jp = 0; jp < npair; ++jp) {
        if (jp > 0) {
            if (jp + 1 < npair) WAIT_VM4(); else WAIT_VM0();
            wg_barrier();
        }
        const int myt = 2*jp + wsid;
        const int s0 = myt * 64;
        const unsigned short* Kc = &Lds[jp & 1][wsid][0][0];
        const unsigned short* Vc = &Lds[jp & 1][wsid][1][0];

        if (myt <= qtH) {
            const bool doL = (myt <= p);
            bf16x8 kb[4][2];
            #pragma unroll
            for (int nt = 0; nt < 4; ++nt) {
                const unsigned short* kr = Kc + (nt*16 + l15)*64;
                kb[nt][0] = *(const bf16x8*)(kr + ((quad    ) ^ (l15 & 7))*8);
                kb[nt][1] = *(const bf16x8*)(kr + ((quad + 4) ^ (l15 & 7))*8);
            }
            f32x4 svH[4], svL[4];
            __builtin_amdgcn_s_setprio(1);
            #pragma unroll
            for (int nt = 0; nt < 4; ++nt) {
                f32x4 z = (f32x4)0.f;
                z = MFMA(kb[nt][0], qfH[0], z);
                z = MFMA(kb[nt][1], qfH[1], z);
                svH[nt] = z;
            }
            if (doL) {
                #pragma unroll
                for (int nt = 0; nt < 4; ++nt) {
                    f32x4 z = (f32x4)0.f;
                    z = MFMA(kb[nt][0], qfL[0], z);
                    z = MFMA(kb[nt][1], qfL[1], z);
                    svL[nt] = z;
                }
            }
            __builtin_amdgcn_s_setprio(0);

            bf16x8 paH[2], paL[2];
            MA_SM(svH, paH, RrH, qw0H);
            if (doL) MA_SM(svL, paL, RrL, qw0L);

            bf16x8 vb[4][2];
            #pragma unroll
            for (int nt = 0; nt < 4; ++nt) {
                const unsigned short* vr = Vc + (nt*16 + l15)*64;
                vb[nt][0] = *(const bf16x8*)(vr + ((cq    ) ^ (l15 & 7))*8);
                vb[nt][1] = *(const bf16x8*)(vr + ((cq + 4) ^ (l15 & 7))*8);
            }
            __builtin_amdgcn_s_setprio(1);
            #pragma unroll
            for (int nt = 0; nt < 4; ++nt) {
                oH[nt] = MFMA(paH[0], vb[nt][0], oH[nt]);
                oH[nt] = MFMA(paH[1], vb[nt][1], oH[nt]);
            }
            if (doL) {
                #pragma unroll
                for (int nt = 0; nt < 4; ++nt) {
                    oL[nt] = MFMA(paL[0], vb[nt][0], oL[nt]);
                    oL[nt] = MFMA(paL[1], vb[nt][1], oL[nt]);
                }
            }
            __builtin_amdgcn_s_setprio(0);
        }

        WAIT_LGKM0();
        wg_barrier();
        if (jp + 2 < npair) {
            const int t0 = 2*(jp + 2);
            const int t1 = min(t0 + 1, nit - 1);
            stage_tile<64, 8>(kg + (size_t)t0*64*DDE, DDE, &Lds[jp & 1][0][0][0], wave, lane);
            stage_tile<64, 8>(eg + t0*64, TT, &Lds[jp & 1][0][1][0], wave, lane);
            stage_tile<64, 8>(kg + (size_t)t1*64*DDE, DDE, &Lds[jp & 1][1][0][0], wave, lane);
            stage_tile<64, 8>(eg + t1*64, TT, &Lds[jp & 1][1][1][0], wave, lane);
        }
    }

    // merge partials across the ws-pair: ws=0 ships H-set, ws=1 ships L-set.
    float* S = (float*)&Lds[0][0][0][0];
    float* my = S + (size_t)(wave*64 + lane)*16;
    {
        const f32x4 (&os)[4] = wsid ? oL : oH;
        #pragma unroll
        for (int nt = 0; nt < 4; ++nt)
            #pragma unroll
            for (int r = 0; r < 4; ++r) my[nt*4 + r] = os[nt][r];
    }
    WAIT_LGKM0();
    wg_barrier();
    const float* peer = S + (size_t)((wave ^ 4)*64 + lane)*16;
    f32x4 (&ok)[4] = wsid ? oH : oL;
    #pragma unroll
    for (int nt = 0; nt < 4; ++nt)
        #pragma unroll
        for (int r = 0; r < 4; ++r) ok[nt][r] += peer[nt*4 + r];

    // store with fused combine: ws=0 -> qtL rows, ws=1 -> qtH rows
    const int qt = wsid ? qtH : qtL;
    #pragma unroll
    for (int nt = 0; nt < 4; ++nt)
        #pragma unroll
        for (int r = 0; r < 4; ++r) {
            const int row = qt*64 + wl*16 + quad*4 + r;
            const int col = h*HDD + nt*16 + l15;
            const size_t e = (size_t)(b*TT + row)*DDE + col;
            ysumb[e] = (bf16_t)((float)yarb[e] + ok[nt][r]);
        }
}

// ---------------------------------------------------------------------------
extern "C" void kernel_launch(void* const* d_in, const int* in_sizes, int n_in,
                              void* d_out, int out_size, void* d_ws, size_t ws_size,
                              hipStream_t stream)
{
    const float* x      = (const float*)d_in[0];
    const float* w_attn = (const float*)d_in[1];
    const float* b_attn = (const float*)d_in[2];
    const float* w_k2   = (const float*)d_in[3];
    const float* b_k2   = (const float*)d_in[4];
    const float* w_proj = (const float*)d_in[5];
    const float* b_proj = (const float*)d_in[6];

    const size_t NX  = (size_t)BB*TT*DDE;
    const size_t NWA = (size_t)2*DDE*DDE;
    const size_t NW  = (size_t)DDE*DDE;
    const size_t NQK = (size_t)BB*TT*2*DDE;

    bf16_t* xb   = (bf16_t*)d_ws;
    bf16_t* wab  = xb   + NX;
    bf16_t* wkb  = wab  + NWA;
    bf16_t* wpb  = wkb  + NW;
    bf16_t* qkb  = wpb  + NW;
    bf16_t* qab  = qkb  + NQK;
    bf16_t* kcs  = qab  + NX;
    bf16_t* vtg  = kcs  + NX;          // aliased by etg after attn_ar
    bf16_t* ysumb= vtg  + NX;
    bf16_t* yarb = (bf16_t*)((float*)(vtg + NX) + NX);
    bf16_t* etg  = vtg;

    const size_t NCVT = NX + NWA + NW + NW;
    cvt_all<<<NCVT / 1024, 256, 0, stream>>>(x, w_attn, w_k2, w_proj, xb);

    transpose_head<<<dim3(TT/64, NHH, BB), 256, 0, stream>>>(xb, vtg);

    const int M = BB * TT;
    gemm_qkk2<<<dim3(24, M/64), 256, 0, stream>>>(xb, wab, wkb, b_attn, b_k2,
                                                   qkb, qab, kcs);

    attn_ar_mfma<<<dim3(16, NHH, BB), 512, 0, stream>>>(qkb, vtg, yarb);
    build_etg<<<dim3(TT/64, NHH, BB), 256, 0, stream>>>(yarb, xb, etg);
    attn_ma_mfma<<<dim3(16, NHH, BB), 512, 0, stream>>>(qab, kcs, etg, yarb, ysumb);

    gemm_proj<<<dim3(DDE/64, M/64), 256, 0, stream>>>(ysumb, wpb, b_proj,
                                                      (float*)d_out, M, DDE, DDE, 2.f);
}

// Round 14
// 214.066 us; speedup vs baseline: 1.2198x; 1.2198x over previous
//
#include <hip/hip_runtime.h>
#include <hip/hip_bf16.h>
#include <math.h>

#define BB  2
#define TT  2048
#define DDE 1024
#define NHH 16
#define HDD 64

typedef __bf16 bf16_t;
typedef __attribute__((ext_vector_type(8))) __bf16 bf16x8;
typedef __attribute__((ext_vector_type(4))) __bf16 bf16x4;
typedef __attribute__((ext_vector_type(4))) float  f32x4;

#define MFMA(a, b, c) __builtin_amdgcn_mfma_f32_16x16x32_bf16((a), (b), (c), 0, 0, 0)

// counted waits: loads for the NEXT tile stay in flight across barriers (T4)
#define WAIT_VM6()   asm volatile("s_waitcnt vmcnt(6)" ::: "memory")
#define WAIT_VM4()   asm volatile("s_waitcnt vmcnt(4)" ::: "memory")
#define WAIT_VM0()   asm volatile("s_waitcnt vmcnt(0)" ::: "memory")
#define WAIT_LGKM0() asm volatile("s_waitcnt lgkmcnt(0)" ::: "memory")

// raw workgroup barrier (no vmcnt drain), fenced against compiler reordering
__device__ inline void wg_barrier() {
    __builtin_amdgcn_sched_barrier(0);
    __builtin_amdgcn_s_barrier();
    __builtin_amdgcn_sched_barrier(0);
}

// pack 2 f32 -> 1 u32 of 2 bf16 (RNE), no builtin on gfx950
__device__ inline unsigned int cvtpk(float a, float b) {
    unsigned int r;
    asm("v_cvt_pk_bf16_f32 %0, %1, %2" : "=v"(r) : "v"(a), "v"(b));
    return r;
}

// single-instruction 2^x (exact; denormals flush->0, fine for softmax)
__device__ inline float fexp2(float x) {
    float r;
    asm("v_exp_f32 %0, %1" : "=v"(r) : "v"(x));
    return r;
}

// v_permlane16_swap_b32: swaps a's odd 16-lane rows with b's even 16-lane
// rows.  After: a = {a.r0, b.r0, a.r2, b.r2}, b = {a.r1, b.r1, a.r3, b.r3}.
__device__ inline void pl16swap(unsigned int &a, unsigned int &b) {
    asm("v_permlane16_swap_b32 %0, %1" : "+v"(a), "+v"(b));
}

__device__ inline void gll16(const bf16_t* g, unsigned short* l) {
    __builtin_amdgcn_global_load_lds(
        (const __attribute__((address_space(1))) void*)g,
        (__attribute__((address_space(3))) void*)l, 16, 0, 0);
}

// Stage [ROWS x 64] bf16 tile (row stride gstride elems) into LDS via
// global_load_lds, chunk-swizzled: LDS elem [r][ (c ^ (r&7))*8 + j ].
// Per-wave gll16 count: ROWS/(NW*8).
template<int ROWS, int NW = 4>
__device__ inline void stage_tile(const bf16_t* g0, size_t gstride,
                                  unsigned short* lds, int wave, int lane)
{
    const int r8 = lane >> 3;
    const int ck = (lane & 7) ^ r8;
    constexpr int RW = ROWS / NW;
    const bf16_t* g = g0 + (size_t)(wave * RW + r8) * gstride + ck * 8;
    unsigned short* l = lds + wave * RW * 64 + lane * 8;
    #pragma unroll
    for (int i = 0; i < RW / 8; ++i)
        gll16(g + (size_t)(i * 8) * gstride, l + i * 512);
}

// ---------------------------------------------------------------------------
// fused fp32->bf16 conversion of x, w_attn, w_k2, w_proj into the contiguous
// ws region starting at xb.  Segment boundaries are multiples of 1024 elems.
// ---------------------------------------------------------------------------
__global__ __launch_bounds__(256) void cvt_all(
    const float* __restrict__ x, const float* __restrict__ wa,
    const float* __restrict__ wk, const float* __restrict__ wp,
    bf16_t* __restrict__ out)
{
    const size_t NX  = (size_t)BB*TT*DDE;
    const size_t NWA = (size_t)2*DDE*DDE;
    const size_t NW  = (size_t)DDE*DDE;
    const size_t e = ((size_t)blockIdx.x * 256 + threadIdx.x) * 4;
    const float* src;
    if (e < NX)                 src = x  + e;
    else if (e < NX + NWA)      src = wa + (e - NX);
    else if (e < NX + NWA + NW) src = wk + (e - NX - NWA);
    else                        src = wp + (e - NX - NWA - NW);
    float4 v = *(const float4*)src;
    bf16x4 o;
    o[0] = (bf16_t)v.x; o[1] = (bf16_t)v.y;
    o[2] = (bf16_t)v.z; o[3] = (bf16_t)v.w;
    *(bf16x4*)(out + e) = o;
}

// ---------------------------------------------------------------------------
// Per-head 64x64 transpose: dst[bh][d][t] = src[b][t][h*64+d].
// ---------------------------------------------------------------------------
__global__ __launch_bounds__(256) void transpose_head(
    const bf16_t* __restrict__ src, bf16_t* __restrict__ dst)
{
    const int t0 = blockIdx.x * 64, h = blockIdx.y, b = blockIdx.z;
    const int tid = threadIdx.x;
    __shared__ __align__(16) bf16_t tile[64 * 64];

    #pragma unroll
    for (int it = 0; it < 2; ++it) {
        const int t = it * 32 + (tid >> 3);
        const int cw = tid & 7;
        const int slot = (cw + (t >> 3)) & 7;
        bf16x8 v = *(const bf16x8*)(src + (size_t)(b*TT + t0 + t)*DDE + h*HDD + cw*8);
        *(bf16x8*)(tile + t*64 + slot*8) = v;
    }
    __syncthreads();
    const int bh = b * NHH + h;
    #pragma unroll
    for (int it = 0; it < 2; ++it) {
        const int d = it * 32 + (tid >> 3);
        const int co = tid & 7;
        const int slot = ((d >> 3) + co) & 7;
        bf16x8 o;
        #pragma unroll
        for (int j = 0; j < 8; ++j)
            o[j] = tile[(co*8 + j)*64 + slot*8 + (d & 7)];
        *(bf16x8*)(dst + (size_t)(bh*64 + d)*TT + t0 + co*8) = o;
    }
}

// ---------------------------------------------------------------------------
// E-transpose: etg[bh][d][t] = x[t][d] - n[t-1][d]  (0 at t==0),
// where n = yarb (normalized AR output, written by attn_ar).
// ---------------------------------------------------------------------------
__global__ __launch_bounds__(256) void build_etg(
    const bf16_t* __restrict__ yarb, const bf16_t* __restrict__ xb,
    bf16_t* __restrict__ etg)
{
    const int t0 = blockIdx.x * 64, h = blockIdx.y, b = blockIdx.z;
    const int tid = threadIdx.x;
    const int bh = b * NHH + h;
    __shared__ __align__(16) bf16_t tile[64 * 64];

    #pragma unroll
    for (int it = 0; it < 2; ++it) {
        const int t = it * 32 + (tid >> 3);
        const int cw = tid & 7;
        const int slot = (cw + (t >> 3)) & 7;
        const int tg = t0 + t;
        bf16x8 ev;
        if (tg == 0) {
            #pragma unroll
            for (int u = 0; u < 8; ++u) ev[u] = (bf16_t)0.f;
        } else {
            bf16x8 xv = *(const bf16x8*)(xb   + (size_t)(b*TT + tg)*DDE + h*HDD + cw*8);
            bf16x8 nv = *(const bf16x8*)(yarb + (size_t)(b*TT + tg - 1)*DDE + h*HDD + cw*8);
            #pragma unroll
            for (int u = 0; u < 8; ++u)
                ev[u] = (bf16_t)((float)xv[u] - (float)nv[u]);
        }
        *(bf16x8*)(tile + t*64 + slot*8) = ev;
    }
    __syncthreads();
    #pragma unroll
    for (int it = 0; it < 2; ++it) {
        const int d = it * 32 + (tid >> 3);
        const int co = tid & 7;
        const int slot = ((d >> 3) + co) & 7;
        bf16x8 o;
        #pragma unroll
        for (int j = 0; j < 8; ++j)
            o[j] = tile[(co*8 + j)*64 + slot*8 + (d & 7)];
        *(bf16x8*)(etg + (size_t)(bh*64 + d)*TT + t0 + co*8) = o;
    }
}

// ---------------------------------------------------------------------------
// Fused QKV GEMM, BM=64 x BN=128, BK=64, counted-vmcnt dbuf pipeline
// (round-10/12 proven config: ~46us / 561 TF).  Region by column tile:
//   [0,1024):  q -> qkb = q*0.125*log2(e) (exp2 domain), qab = leaky(q*0.125)
//   [1024,2048): k -> qkb raw
//   [2048,3072): k2 -> kcs[t+1] = sigmoid(k2*0.0025)-0.5 (shifted, row0=0)
// ---------------------------------------------------------------------------
__global__ __launch_bounds__(256) void gemm_qkk2(
    const bf16_t* __restrict__ A, const bf16_t* __restrict__ wab,
    const bf16_t* __restrict__ wkb, const float* __restrict__ b_attn,
    const float* __restrict__ b_k2, bf16_t* __restrict__ qkb,
    bf16_t* __restrict__ qab, bf16_t* __restrict__ kcs)
{
    __shared__ __align__(16) unsigned short As[2][64 * 64];
    __shared__ __align__(16) unsigned short Bs[2][128 * 64];
    const int tid  = threadIdx.x;
    const int wave = tid >> 6, lane = tid & 63;
    const int l15  = lane & 15, quad = lane >> 4;
    // XCD swizzle (bijective: 1536 = 8*192): each XCD owns 8 contiguous
    // m-rows x all 24 n-tiles; per-k-step slab (A 64KB + B 384KB) L2-fits.
    const int lid = (int)blockIdx.y * 24 + (int)blockIdx.x;
    const int s   = (lid & 7) * 192 + (lid >> 3);
    const int bm = (s / 24) * 64, bn = (s % 24) * 128;
    const int wm = (wave & 1) * 32, wn = (wave >> 1) * 64;
    const int region = bn >> 10;
    const int K = DDE;
    constexpr int NST = DDE / 64;   // 16 K-steps

    const bf16_t* W = (region < 2) ? wab + (size_t)bn * K
                                   : wkb + (size_t)(bn - 2048) * K;
    const float* bp = (region < 2) ? b_attn + bn : b_k2 + (bn - 2048);
    const bf16_t* Ab = A + (size_t)bm * K;

    f32x4 acc[2][4];
    #pragma unroll
    for (int i = 0; i < 2; ++i)
        #pragma unroll
        for (int j = 0; j < 4; ++j) acc[i][j] = (f32x4)0.f;

    // prologue: stage K-steps 0 and 1 (6 gll16/wave each: 2 A + 4 B)
    stage_tile<64>(Ab, K, As[0], wave, lane);
    stage_tile<128>(W,  K, Bs[0], wave, lane);
    stage_tile<64>(Ab + 64, K, As[1], wave, lane);
    stage_tile<128>(W  + 64, K, Bs[1], wave, lane);

    for (int t = 0; t < NST; ++t) {
        // wait tile t landed; tile t+1's 6 loads stay in flight
        if (t + 1 < NST) WAIT_VM6(); else WAIT_VM0();
        wg_barrier();
        const unsigned short* Ac = As[t & 1];
        const unsigned short* Bc = Bs[t & 1];
        bf16x8 af[2][2], bfr[4][2];
        #pragma unroll
        for (int mt = 0; mt < 2; ++mt)
            #pragma unroll
            for (int kh = 0; kh < 2; ++kh)
                af[mt][kh] = *(const bf16x8*)(Ac + (wm + mt*16 + l15)*64
                                              + (((kh*4 + quad) ^ (l15 & 7))*8));
        #pragma unroll
        for (int nt = 0; nt < 4; ++nt)
            #pragma unroll
            for (int kh = 0; kh < 2; ++kh)
                bfr[nt][kh] = *(const bf16x8*)(Bc + (wn + nt*16 + l15)*64
                                               + (((kh*4 + quad) ^ (l15 & 7))*8));
        __builtin_amdgcn_s_setprio(1);
        #pragma unroll
        for (int mt = 0; mt < 2; ++mt)
            #pragma unroll
            for (int nt = 0; nt < 4; ++nt) {
                acc[mt][nt] = MFMA(af[mt][0], bfr[nt][0], acc[mt][nt]);
                acc[mt][nt] = MFMA(af[mt][1], bfr[nt][1], acc[mt][nt]);
            }
        __builtin_amdgcn_s_setprio(0);
        // all waves done reading buf[t&1] before restaging into it
        WAIT_LGKM0();
        wg_barrier();
        if (t + 2 < NST) {
            stage_tile<64>(Ab + (t+2)*64, K, As[t & 1], wave, lane);
            stage_tile<128>(W  + (t+2)*64, K, Bs[t & 1], wave, lane);
        }
    }

    #pragma unroll
    for (int nt = 0; nt < 4; ++nt) {
        const int cl = wn + nt*16 + l15;
        const float bj = bp[cl];
        const int cg = bn + cl;
        #pragma unroll
        for (int mt = 0; mt < 2; ++mt)
            #pragma unroll
            for (int r = 0; r < 4; ++r) {
                const int row = bm + wm + mt*16 + quad*4 + r;
                const float v = acc[mt][nt][r] + bj;
                if (region == 0) {
                    qkb[(size_t)row * (2*DDE) + cg] = (bf16_t)(v * 0.180336880f);
                    const float z = v * 0.125f;
                    qab[(size_t)row * DDE + cg] = (bf16_t)((v > 0.f) ? 0.02f*z : z);
                } else if (region == 1) {
                    qkb[(size_t)row * (2*DDE) + cg] = (bf16_t)v;
                } else {
                    const int c2 = cg - 2048;
                    const float kc = 1.f/(1.f + __expf(-v*0.0025f)) - 0.5f;
                    if (((row + 1) & (TT - 1)) != 0)
                        kcs[(size_t)(row + 1) * DDE + c2] = (bf16_t)kc;
                    if ((row & (TT - 1)) == 0)
                        kcs[(size_t)row * DDE + c2] = (bf16_t)0.f;
                }
            }
    }
}

// ---------------------------------------------------------------------------
// proj GEMM, BM=64 x BN=64, BK=64, counted-vmcnt dbuf (fp32 out):
// C = A W^T + 2*bias.  1024 blocks (4/CU by grid, 5/CU by LDS=32KB).
// ---------------------------------------------------------------------------
__global__ __launch_bounds__(256) void gemm_proj(
    const bf16_t* __restrict__ A, const bf16_t* __restrict__ W,
    const float* __restrict__ bias, float* __restrict__ C,
    int M, int N, int K, float bmul)
{
    __shared__ __align__(16) unsigned short As[2][64 * 64];
    __shared__ __align__(16) unsigned short Bs[2][64 * 64];
    const int tid  = threadIdx.x;
    const int wave = tid >> 6, lane = tid & 63;
    const int l15  = lane & 15, quad = lane >> 4;
    // XCD swizzle (bijective: 1024 = 8*128)
    const int lid = (int)blockIdx.y * 16 + (int)blockIdx.x;
    const int s   = (lid & 7) * 128 + (lid >> 3);
    const int bm = (s / 16) * 64, bn = (s % 16) * 64;
    const int wm = (wave & 1) * 32, wn = (wave >> 1) * 32;

    const bf16_t* Ab = A + (size_t)bm * K;
    const bf16_t* Wb = W + (size_t)bn * K;
    const int NST = K / 64;

    f32x4 acc[2][2];
    #pragma unroll
    for (int i = 0; i < 2; ++i)
        #pragma unroll
        for (int j = 0; j < 2; ++j) acc[i][j] = (f32x4)0.f;

    stage_tile<64>(Ab, K, As[0], wave, lane);
    stage_tile<64>(Wb, K, Bs[0], wave, lane);
    stage_tile<64>(Ab + 64, K, As[1], wave, lane);
    stage_tile<64>(Wb + 64, K, Bs[1], wave, lane);

    for (int t = 0; t < NST; ++t) {
        if (t + 1 < NST) WAIT_VM4(); else WAIT_VM0();
        wg_barrier();
        const unsigned short* Ac = As[t & 1];
        const unsigned short* Bc = Bs[t & 1];
        bf16x8 af[2][2], bfr[2][2];
        #pragma unroll
        for (int mt = 0; mt < 2; ++mt)
            #pragma unroll
            for (int kh = 0; kh < 2; ++kh)
                af[mt][kh] = *(const bf16x8*)(Ac + (wm + mt*16 + l15)*64
                                              + (((kh*4 + quad) ^ (l15 & 7))*8));
        #pragma unroll
        for (int nt = 0; nt < 2; ++nt)
            #pragma unroll
            for (int kh = 0; kh < 2; ++kh)
                bfr[nt][kh] = *(const bf16x8*)(Bc + (wn + nt*16 + l15)*64
                                               + (((kh*4 + quad) ^ (l15 & 7))*8));
        __builtin_amdgcn_s_setprio(1);
        #pragma unroll
        for (int mt = 0; mt < 2; ++mt)
            #pragma unroll
            for (int nt = 0; nt < 2; ++nt) {
                acc[mt][nt] = MFMA(af[mt][0], bfr[nt][0], acc[mt][nt]);
                acc[mt][nt] = MFMA(af[mt][1], bfr[nt][1], acc[mt][nt]);
            }
        __builtin_amdgcn_s_setprio(0);
        WAIT_LGKM0();
        wg_barrier();
        if (t + 2 < NST) {
            stage_tile<64>(Ab + (t+2)*64, K, As[t & 1], wave, lane);
            stage_tile<64>(Wb + (t+2)*64, K, Bs[t & 1], wave, lane);
        }
    }

    #pragma unroll
    for (int nt = 0; nt < 2; ++nt) {
        const int col = bn + wn + nt*16 + l15;
        const float bj = bias[col] * bmul;
        #pragma unroll
        for (int mt = 0; mt < 2; ++mt)
            #pragma unroll
            for (int r = 0; r < 4; ++r) {
                const int row = bm + wm + mt*16 + quad*4 + r;
                C[(size_t)row * N + col] = acc[mt][nt][r] + bj;
            }
    }
}

// per-unit AR compute on tile (Kc,Vc,s0): QK^T (swapped), softmax-exp,
// permlane repack, ones-MFMA denominator, PV accumulate.
#define AR_UNIT(QF, OO, LSACC, QW0)  do {                                   \
    f32x4 sv[4];                                                            \
    __builtin_amdgcn_s_setprio(1);                                          \
    _Pragma("unroll")                                                       \
    for (int nt = 0; nt < 4; ++nt) {                                        \
        const unsigned short* kr = Kc + (nt*16 + l15)*64;                   \
        bf16x8 kb0 = *(const bf16x8*)(kr + ((quad    ) ^ (l15 & 7))*8);     \
        bf16x8 kb1 = *(const bf16x8*)(kr + ((quad + 4) ^ (l15 & 7))*8);     \
        f32x4 z = (f32x4)0.f;                                               \
        z = MFMA(kb0, QF[0], z);                                            \
        z = MFMA(kb1, QF[1], z);                                            \
        sv[nt] = z;                                                         \
    }                                                                       \
    __builtin_amdgcn_s_setprio(0);                                          \
    const bool domask = (s0 + 63 > (QW0));                                  \
    const int qg = (QW0) + l15;                                             \
    unsigned int pk[4][2];                                                  \
    _Pragma("unroll")                                                       \
    for (int nt = 0; nt < 4; ++nt) {                                        \
        float pv[4];                                                        \
        _Pragma("unroll")                                                   \
        for (int r = 0; r < 4; ++r) {                                       \
            float pe = fexp2(sv[nt][r]);                                    \
            if (domask) {                                                   \
                const int sg = s0 + nt*16 + quad*4 + r;                     \
                if (sg > qg) pe = 0.f;                                      \
            }                                                               \
            pv[r] = pe;                                                     \
        }                                                                   \
        pk[nt][0] = cvtpk(pv[0], pv[1]);                                    \
        pk[nt][1] = cvtpk(pv[2], pv[3]);                                    \
    }                                                                       \
    bf16x8 pa[2];                                                           \
    _Pragma("unroll")                                                       \
    for (int sc = 0; sc < 2; ++sc) {                                        \
        pl16swap(pk[2*sc][0], pk[2*sc+1][0]);                               \
        pl16swap(pk[2*sc][1], pk[2*sc+1][1]);                               \
        union { unsigned int uu[4]; bf16x8 v; } pu;                         \
        pu.uu[0] = pk[2*sc][0];   pu.uu[1] = pk[2*sc][1];                   \
        pu.uu[2] = pk[2*sc+1][0]; pu.uu[3] = pk[2*sc+1][1];                 \
        pa[sc] = pu.v;                                                      \
    }                                                                       \
    __builtin_amdgcn_s_setprio(1);                                          \
    LSACC = MFMA(pa[0], onesb, LSACC);                                      \
    LSACC = MFMA(pa[1], onesb, LSACC);                                      \
    _Pragma("unroll")                                                       \
    for (int nt = 0; nt < 4; ++nt) {                                        \
        const unsigned short* vr = Vc + (nt*16 + l15)*64;                   \
        bf16x8 vb0 = *(const bf16x8*)(vr + ((cq    ) ^ (l15 & 7))*8);       \
        bf16x8 vb1 = *(const bf16x8*)(vr + ((cq + 4) ^ (l15 & 7))*8);       \
        OO[nt] = MFMA(pa[0], vb0, OO[nt]);                                  \
        OO[nt] = MFMA(pa[1], vb1, OO[nt]);                                  \
    }                                                                       \
    __builtin_amdgcn_s_setprio(0);                                          \
} while (0)

// ---------------------------------------------------------------------------
// AR: fixed-max flash attention, work-conserving paired decomposition.
// Block owns q-tiles (p, 31-p).  Per kv-pair iteration, wave takes tile
// myt = 2*jp + (wave>=4) and processes up to TWO units on it: (qtH,myt) and
// (qtL,myt) -> every wave ~16.5 units regardless of p (no idle waves).
// Even/odd-tile partials merge across the ws-pair through LDS at the end.
// ---------------------------------------------------------------------------
__global__ __launch_bounds__(512, 4) void attn_ar_mfma(
    const bf16_t* __restrict__ qkb, const bf16_t* __restrict__ vtg,
    bf16_t* __restrict__ yarb)
{
    const int h = blockIdx.y, b = blockIdx.z;
    const int p = b ? (15 - (int)blockIdx.x) : (int)blockIdx.x;  // co-CU hedge
    const int qtL = p, qtH = 31 - p;
    const int tid = threadIdx.x, wave = tid >> 6, lane = tid & 63;
    const int l15 = lane & 15, quad = lane >> 4;
    const int wl = wave & 3, wsid = wave >> 2;
    const int qw0L = qtL * 64 + wl * 16;
    const int qw0H = qtH * 64 + wl * 16;
    const int bh = b * NHH + h;

    // [pair][half][K=0/V=1][64*64] = 64 KB; reused as f32 merge scratch.
    __shared__ __align__(16) unsigned short Lds[2][2][2][64 * 64];

    const int nit = qtH + 1;          // kv tiles 0 .. qtH  (>= 17)
    const int npair = (nit + 1) >> 1;

    const bf16_t* kg = qkb + (size_t)(b*TT)*(2*DDE) + DDE + h*HDD;
    const bf16_t* vg = vtg + (size_t)(bh*64)*TT;

    // Q fragments for both targets: direct global->reg.
    const bf16_t* qrowL = qkb + (size_t)(b*TT + qw0L + l15)*(2*DDE) + h*HDD;
    const bf16_t* qrowH = qkb + (size_t)(b*TT + qw0H + l15)*(2*DDE) + h*HDD;
    bf16x8 qfL[2], qfH[2];
    qfL[0] = *(const bf16x8*)(qrowL + quad*8);
    qfL[1] = *(const bf16x8*)(qrowL + (quad + 4)*8);
    qfH[0] = *(const bf16x8*)(qrowH + quad*8);
    qfH[1] = *(const bf16x8*)(qrowH + (quad + 4)*8);
    __builtin_amdgcn_sched_barrier(0);   // pin Q-load issue before staging

    // prologue: pairs 0 (tiles 0,1) and 1 (tiles 2,3); 4 loads/wave/pair
    stage_tile<64, 8>(kg, 2*DDE, &Lds[0][0][0][0], wave, lane);
    stage_tile<64, 8>(vg, TT,    &Lds[0][0][1][0], wave, lane);
    stage_tile<64, 8>(kg + (size_t)64*(2*DDE), 2*DDE, &Lds[0][1][0][0], wave, lane);
    stage_tile<64, 8>(vg + 64, TT, &Lds[0][1][1][0], wave, lane);
    stage_tile<64, 8>(kg + (size_t)2*64*(2*DDE), 2*DDE, &Lds[1][0][0][0], wave, lane);
    stage_tile<64, 8>(vg + 2*64, TT, &Lds[1][0][1][0], wave, lane);
    stage_tile<64, 8>(kg + (size_t)3*64*(2*DDE), 2*DDE, &Lds[1][1][0][0], wave, lane);
    stage_tile<64, 8>(vg + 3*64, TT, &Lds[1][1][1][0], wave, lane);
    WAIT_VM4();            // Q + pair0 landed, pair1 in flight
    wg_barrier();

    f32x4 oH[4], oL[4];
    f32x4 lsH = (f32x4)0.f, lsL = (f32x4)0.f;
    #pragma unroll
    for (int nt = 0; nt < 4; ++nt) { oH[nt] = (f32x4)0.f; oL[nt] = (f32x4)0.f; }
    bf16x8 onesb;
    #pragma unroll
    for (int j = 0; j < 8; ++j) onesb[j] = (bf16_t)1.f;

    // after permlane repack, quad q holds key-chunk cq = bitswap(q)
    const int cq = ((quad & 1) << 1) | (quad >> 1);

    for (int jp = 0; jp < npair; ++jp) {
        if (jp > 0) {
            if (jp + 1 < npair) WAIT_VM4(); else WAIT_VM0();
            wg_barrier();
        }
        const int myt = 2*jp + wsid;
        const int s0 = myt * 64;
        const unsigned short* Kc = &Lds[jp & 1][wsid][0][0];
        const unsigned short* Vc = &Lds[jp & 1][wsid][1][0];

        if (myt <= qtH) AR_UNIT(qfH, oH, lsH, qw0H);
        if (myt <= p)   AR_UNIT(qfL, oL, lsL, qw0L);

        WAIT_LGKM0();
        wg_barrier();
        if (jp + 2 < npair) {
            const int t0 = 2*(jp + 2);              // always < nit
            const int t1 = min(t0 + 1, nit - 1);    // clamp (uniform vmcnt)
            stage_tile<64, 8>(kg + (size_t)t0*64*(2*DDE), 2*DDE, &Lds[jp & 1][0][0][0], wave, lane);
            stage_tile<64, 8>(vg + t0*64, TT, &Lds[jp & 1][0][1][0], wave, lane);
            stage_tile<64, 8>(kg + (size_t)t1*64*(2*DDE), 2*DDE, &Lds[jp & 1][1][0][0], wave, lane);
            stage_tile<64, 8>(vg + t1*64, TT, &Lds[jp & 1][1][1][0], wave, lane);
        }
    }
    // here: vmcnt==0 (final iter waited VM0, no further stages); LDS reusable.

    // merge partials across the ws-pair: ws=0 ships H-set, ws=1 ships L-set.
    float* S = (float*)&Lds[0][0][0][0];
    float* my = S + (size_t)(wave*64 + lane)*20;
    {
        const f32x4 (&os)[4] = wsid ? oL : oH;
        const f32x4 &lss     = wsid ? lsL : lsH;
        #pragma unroll
        for (int nt = 0; nt < 4; ++nt)
            #pragma unroll
            for (int r = 0; r < 4; ++r) my[nt*4 + r] = os[nt][r];
        #pragma unroll
        for (int r = 0; r < 4; ++r) my[16 + r] = lss[r];
    }
    WAIT_LGKM0();
    wg_barrier();
    const float* peer = S + (size_t)((wave ^ 4)*64 + lane)*20;
    f32x4 (&ok)[4] = wsid ? oH : oL;   // kept set (the one not shipped)
    f32x4 &lsk     = wsid ? lsH : lsL;
    #pragma unroll
    for (int nt = 0; nt < 4; ++nt)
        #pragma unroll
        for (int r = 0; r < 4; ++r) ok[nt][r] += peer[nt*4 + r];
    #pragma unroll
    for (int r = 0; r < 4; ++r) lsk[r] += peer[16 + r];

    // store: ws=0 -> qtL rows, ws=1 -> qtH rows
    const int qt = wsid ? qtH : qtL;
    float inv[4];
    #pragma unroll
    for (int r = 0; r < 4; ++r) inv[r] = 1.f / lsk[r];
    #pragma unroll
    for (int nt = 0; nt < 4; ++nt)
        #pragma unroll
        for (int r = 0; r < 4; ++r) {
            const int row = qt*64 + wl*16 + quad*4 + r;
            const int col = h*HDD + nt*16 + l15;
            yarb[(size_t)(b*TT + row)*DDE + col] = (bf16_t)(ok[nt][r] * inv[r]);
        }
}

// per-unit MA compute (linear attention variant: p = S + Rr, zero masks).
#define MA_UNIT(QF, OO, RR, QW0)  do {                                      \
    f32x4 sv[4];                                                            \
    __builtin_amdgcn_s_setprio(1);                                          \
    _Pragma("unroll")                                                       \
    for (int nt = 0; nt < 4; ++nt) {                                        \
        const unsigned short* kr = Kc + (nt*16 + l15)*64;                   \
        bf16x8 kb0 = *(const bf16x8*)(kr + ((quad    ) ^ (l15 & 7))*8);     \
        bf16x8 kb1 = *(const bf16x8*)(kr + ((quad + 4) ^ (l15 & 7))*8);     \
        f32x4 z = (f32x4)0.f;                                               \
        z = MFMA(kb0, QF[0], z);                                            \
        z = MFMA(kb1, QF[1], z);                                            \
        sv[nt] = z;                                                         \
    }                                                                       \
    __builtin_amdgcn_s_setprio(0);                                          \
    const bool domask = (s0 + 63 > (QW0));                                  \
    const bool m0 = (myt == 0);                                             \
    const int qg = (QW0) + l15;                                             \
    unsigned int pk[4][2];                                                  \
    _Pragma("unroll")                                                       \
    for (int nt = 0; nt < 4; ++nt) {                                        \
        float pv[4];                                                        \
        _Pragma("unroll")                                                   \
        for (int r = 0; r < 4; ++r) {                                       \
            const int sg = s0 + nt*16 + quad*4 + r;                         \
            float pe = sv[nt][r] + (RR);                                    \
            if (m0 && sg == 0) pe = 0.f;                                    \
            if (domask && sg > qg) pe = 0.f;                                \
            pv[r] = pe;                                                     \
        }                                                                   \
        pk[nt][0] = cvtpk(pv[0], pv[1]);                                    \
        pk[nt][1] = cvtpk(pv[2], pv[3]);                                    \
    }                                                                       \
    bf16x8 pa[2];                                                           \
    _Pragma("unroll")                                                       \
    for (int sc = 0; sc < 2; ++sc) {                                        \
        pl16swap(pk[2*sc][0], pk[2*sc+1][0]);                               \
        pl16swap(pk[2*sc][1], pk[2*sc+1][1]);                               \
        union { unsigned int uu[4]; bf16x8 v; } pu;                         \
        pu.uu[0] = pk[2*sc][0];   pu.uu[1] = pk[2*sc][1];                   \
        pu.uu[2] = pk[2*sc+1][0]; pu.uu[3] = pk[2*sc+1][1];                 \
        pa[sc] = pu.v;                                                      \
    }                                                                       \
    __builtin_amdgcn_s_setprio(1);                                          \
    _Pragma("unroll")                                                       \
    for (int nt = 0; nt < 4; ++nt) {                                        \
        const unsigned short* er = Vc + (nt*16 + l15)*64;                   \
        bf16x8 eb0 = *(const bf16x8*)(er + ((cq    ) ^ (l15 & 7))*8);       \
        bf16x8 eb1 = *(const bf16x8*)(er + ((cq + 4) ^ (l15 & 7))*8);       \
        OO[nt] = MFMA(pa[0], eb0, OO[nt]);                                  \
        OO[nt] = MFMA(pa[1], eb1, OO[nt]);                                  \
    }                                                                       \
    __builtin_amdgcn_s_setprio(0);                                          \
} while (0)

// ---------------------------------------------------------------------------
// MA: linear causal attention, same work-conserving paired structure.
// Q row-sums in-register for both targets; merge across ws-pair; fused
// combine epilogue: ysumb = bf16(yarb + o).
// ---------------------------------------------------------------------------
__global__ __launch_bounds__(512, 4) void attn_ma_mfma(
    const bf16_t* __restrict__ qab, const bf16_t* __restrict__ kcs,
    const bf16_t* __restrict__ etg, const bf16_t* __restrict__ yarb,
    bf16_t* __restrict__ ysumb)
{
    const int h = blockIdx.y, b = blockIdx.z;
    const int p = b ? (15 - (int)blockIdx.x) : (int)blockIdx.x;
    const int qtL = p, qtH = 31 - p;
    const int tid = threadIdx.x, wave = tid >> 6, lane = tid & 63;
    const int l15 = lane & 15, quad = lane >> 4;
    const int wl = wave & 3, wsid = wave >> 2;
    const int qw0L = qtL * 64 + wl * 16;
    const int qw0H = qtH * 64 + wl * 16;
    const int bh = b * NHH + h;

    __shared__ __align__(16) unsigned short Lds[2][2][2][64 * 64];

    const int nit = qtH + 1;
    const int npair = (nit + 1) >> 1;

    const bf16_t* kg = kcs + (size_t)(b*TT)*DDE + h*HDD;
    const bf16_t* eg = etg + (size_t)(bh*64)*TT;

    const bf16_t* qrowL = qab + (size_t)(b*TT + qw0L + l15)*DDE + h*HDD;
    const bf16_t* qrowH = qab + (size_t)(b*TT + qw0H + l15)*DDE + h*HDD;
    bf16x8 qfL[2], qfH[2];
    qfL[0] = *(const bf16x8*)(qrowL + quad*8);
    qfL[1] = *(const bf16x8*)(qrowL + (quad + 4)*8);
    qfH[0] = *(const bf16x8*)(qrowH + quad*8);
    qfH[1] = *(const bf16x8*)(qrowH + (quad + 4)*8);
    __builtin_amdgcn_sched_barrier(0);

    stage_tile<64, 8>(kg, DDE, &Lds[0][0][0][0], wave, lane);
    stage_tile<64, 8>(eg, TT,  &Lds[0][0][1][0], wave, lane);
    stage_tile<64, 8>(kg + (size_t)64*DDE, DDE, &Lds[0][1][0][0], wave, lane);
    stage_tile<64, 8>(eg + 64, TT, &Lds[0][1][1][0], wave, lane);
    stage_tile<64, 8>(kg + (size_t)2*64*DDE, DDE, &Lds[1][0][0][0], wave, lane);
    stage_tile<64, 8>(eg + 2*64, TT, &Lds[1][0][1][0], wave, lane);
    stage_tile<64, 8>(kg + (size_t)3*64*DDE, DDE, &Lds[1][1][0][0], wave, lane);
    stage_tile<64, 8>(eg + 3*64, TT, &Lds[1][1][1][0], wave, lane);
    WAIT_VM4();
    wg_barrier();

    // Q row-sums in-register (quad butterfly yields full 64-col sum per row)
    float rsL = 0.f, rsH = 0.f;
    #pragma unroll
    for (int kc = 0; kc < 2; ++kc)
        #pragma unroll
        for (int u = 0; u < 8; ++u) { rsL += (float)qfL[kc][u]; rsH += (float)qfH[kc][u]; }
    rsL += __shfl_xor(rsL, 16); rsL += __shfl_xor(rsL, 32);
    rsH += __shfl_xor(rsH, 16); rsH += __shfl_xor(rsH, 32);
    const float RrL = 0.5f * rsL;
    const float RrH = 0.5f * rsH;

    f32x4 oH[4], oL[4];
    #pragma unroll
    for (int nt = 0; nt < 4; ++nt) { oH[nt] = (f32x4)0.f; oL[nt] = (f32x4)0.f; }

    const int cq = ((quad & 1) << 1) | (quad >> 1);

    for (int jp = 0; jp < npair; ++jp) {
        if (jp > 0) {
            if (jp + 1 < npair) WAIT_VM4(); else WAIT_VM0();
            wg_barrier();
        }
        const int myt = 2*jp + wsid;
        const int s0 = myt * 64;
        const unsigned short* Kc = &Lds[jp & 1][wsid][0][0];
        const unsigned short* Vc = &Lds[jp & 1][wsid][1][0];

        if (myt <= qtH) MA_UNIT(qfH, oH, RrH, qw0H);
        if (myt <= p)   MA_UNIT(qfL, oL, RrL, qw0L);

        WAIT_LGKM0();
        wg_barrier();
        if (jp + 2 < npair) {
            const int t0 = 2*(jp + 2);
            const int t1 = min(t0 + 1, nit - 1);
            stage_tile<64, 8>(kg + (size_t)t0*64*DDE, DDE, &Lds[jp & 1][0][0][0], wave, lane);
            stage_tile<64, 8>(eg + t0*64, TT, &Lds[jp & 1][0][1][0], wave, lane);
            stage_tile<64, 8>(kg + (size_t)t1*64*DDE, DDE, &Lds[jp & 1][1][0][0], wave, lane);
            stage_tile<64, 8>(eg + t1*64, TT, &Lds[jp & 1][1][1][0], wave, lane);
        }
    }

    // merge partials across the ws-pair: ws=0 ships H-set, ws=1 ships L-set.
    float* S = (float*)&Lds[0][0][0][0];
    float* my = S + (size_t)(wave*64 + lane)*16;
    {
        const f32x4 (&os)[4] = wsid ? oL : oH;
        #pragma unroll
        for (int nt = 0; nt < 4; ++nt)
            #pragma unroll
            for (int r = 0; r < 4; ++r) my[nt*4 + r] = os[nt][r];
    }
    WAIT_LGKM0();
    wg_barrier();
    const float* peer = S + (size_t)((wave ^ 4)*64 + lane)*16;
    f32x4 (&ok)[4] = wsid ? oH : oL;
    #pragma unroll
    for (int nt = 0; nt < 4; ++nt)
        #pragma unroll
        for (int r = 0; r < 4; ++r) ok[nt][r] += peer[nt*4 + r];

    // store with fused combine: ws=0 -> qtL rows, ws=1 -> qtH rows
    const int qt = wsid ? qtH : qtL;
    #pragma unroll
    for (int nt = 0; nt < 4; ++nt)
        #pragma unroll
        for (int r = 0; r < 4; ++r) {
            const int row = qt*64 + wl*16 + quad*4 + r;
            const int col = h*HDD + nt*16 + l15;
            const size_t e = (size_t)(b*TT + row)*DDE + col;
            ysumb[e] = (bf16_t)((float)yarb[e] + ok[nt][r]);
        }
}

// ---------------------------------------------------------------------------
extern "C" void kernel_launch(void* const* d_in, const int* in_sizes, int n_in,
                              void* d_out, int out_size, void* d_ws, size_t ws_size,
                              hipStream_t stream)
{
    const float* x      = (const float*)d_in[0];
    const float* w_attn = (const float*)d_in[1];
    const float* b_attn = (const float*)d_in[2];
    const float* w_k2   = (const float*)d_in[3];
    const float* b_k2   = (const float*)d_in[4];
    const float* w_proj = (const float*)d_in[5];
    const float* b_proj = (const float*)d_in[6];

    const size_t NX  = (size_t)BB*TT*DDE;
    const size_t NWA = (size_t)2*DDE*DDE;
    const size_t NW  = (size_t)DDE*DDE;
    const size_t NQK = (size_t)BB*TT*2*DDE;

    bf16_t* xb   = (bf16_t*)d_ws;
    bf16_t* wab  = xb   + NX;
    bf16_t* wkb  = wab  + NWA;
    bf16_t* wpb  = wkb  + NW;
    bf16_t* qkb  = wpb  + NW;
    bf16_t* qab  = qkb  + NQK;
    bf16_t* kcs  = qab  + NX;
    bf16_t* vtg  = kcs  + NX;          // aliased by etg after attn_ar
    bf16_t* ysumb= vtg  + NX;
    bf16_t* yarb = (bf16_t*)((float*)(vtg + NX) + NX);
    bf16_t* etg  = vtg;

    const size_t NCVT = NX + NWA + NW + NW;
    cvt_all<<<NCVT / 1024, 256, 0, stream>>>(x, w_attn, w_k2, w_proj, xb);

    transpose_head<<<dim3(TT/64, NHH, BB), 256, 0, stream>>>(xb, vtg);

    const int M = BB * TT;
    gemm_qkk2<<<dim3(24, M/64), 256, 0, stream>>>(xb, wab, wkb, b_attn, b_k2,
                                                   qkb, qab, kcs);

    attn_ar_mfma<<<dim3(16, NHH, BB), 512, 0, stream>>>(qkb, vtg, yarb);
    build_etg<<<dim3(TT/64, NHH, BB), 256, 0, stream>>>(yarb, xb, etg);
    attn_ma_mfma<<<dim3(16, NHH, BB), 512, 0, stream>>>(qab, kcs, etg, yarb, ysumb);

    gemm_proj<<<dim3(DDE/64, M/64), 256, 0, stream>>>(ysumb, wpb, b_proj,
                                                      (float*)d_out, M, DDE, DDE, 2.f);
}